// Round 13
// baseline (156.541 us; speedup 1.0000x reference)
//
#include <hip/hip_runtime.h>
#include <stdint.h>
#include <stddef.h>

#define BATCH 65536
#define OUTF  1024
#define INF   128

typedef float f32x4 __attribute__((ext_vector_type(4)));
typedef __bf16 bf16x8 __attribute__((ext_vector_type(8)));

#define WSTRIDE 260   // wave slab row stride (floats): 256 + 4

// RNE float->bf16, packed pair
__device__ inline uint32_t pack_bf16_rne(float a, float b) {
    uint32_t ua = __builtin_bit_cast(uint32_t, a);
    uint32_t ub = __builtin_bit_cast(uint32_t, b);
    ua += 0x7fffu + ((ua >> 16) & 1u);
    ub += 0x7fffu + ((ub >> 16) & 1u);
    return (ua >> 16) | (ub & 0xffff0000u);
}

// Load 8 contiguous fp32, accumulate sum of squares, return bf16x8 fragment.
__device__ inline bf16x8 load_frag_x2(const float* __restrict__ p, float& s) {
    f32x4 v0 = *(const f32x4*)(p);
    f32x4 v1 = *(const f32x4*)(p + 4);
    s += v0.x * v0.x + v0.y * v0.y + v0.z * v0.z + v0.w * v0.w
       + v1.x * v1.x + v1.y * v1.y + v1.z * v1.z + v1.w * v1.w;
    union { uint32_t u[4]; bf16x8 b; } f;
    f.u[0] = pack_bf16_rne(v0.x, v0.y);
    f.u[1] = pack_bf16_rne(v0.z, v0.w);
    f.u[2] = pack_bf16_rne(v1.x, v1.y);
    f.u[3] = pack_bf16_rne(v1.z, v1.w);
    return f.b;
}

// W-only prep: one wave per w-row -> bf16 row + sumsq. 1024 rows, tiny.
__global__ __launch_bounds__(256) void wprep_kernel(
        const float* __restrict__ w, float* __restrict__ w2,
        uint32_t* __restrict__ wb) {
    int gtid = blockIdx.x * 256 + threadIdx.x;
    int row  = gtid >> 6;
    int lane = threadIdx.x & 63;
    if (row >= OUTF) return;
    const float* src = w + (size_t)row * INF;
    float2 v = *(const float2*)(src + lane * 2);
    wb[(size_t)row * 64 + lane] = pack_bf16_rne(v.x, v.y);
    float s = v.x * v.x + v.y * v.y;
    #pragma unroll
    for (int off = 32; off; off >>= 1) s += __shfl_down(s, off);
    if (lane == 0) w2[row] = s;
}

// Row-slab fused kernel: block = 128 rows x 1024 cols (grid 512, 2/CU).
// Processed as 8 row-slabs of 16 rows. Per slab each wave computes
// 16 rows x 256 cols, epilogue -> wave-private LDS [16][260], then stores
// ONE FULL 1KB instruction per row; the 4 waves jointly emit each complete
// 4KB output row, and slabs sweep the block's 512KB region sequentially
// (DRAM row-complete, channel-uniform — fillBuffer-like write stream).
// No barriers in the loop; stores drain async.
__global__ __launch_bounds__(256, 2) void fused_kernel(
        const float* __restrict__ x, const __bf16* __restrict__ wb,
        const float* __restrict__ w2, float* __restrict__ out) {
    int tid  = threadIdx.x;
    int wid  = tid >> 6;
    int lane = tid & 63;
    int l16  = lane & 15;   // fragment row/col
    int lq   = lane >> 4;   // k-quarter (loads) / row-quad (epilogue)

    int c0 = wid * 256;     // this wave's column slice

    __shared__ float sw2[OUTF];
    __shared__ float slab[4][16 * WSTRIDE];   // wave-private pieces
    #pragma unroll
    for (int j = 0; j < 4; ++j)
        sw2[tid + 256 * j] = w2[tid + 256 * j];
    __syncthreads();   // the ONLY barrier

    float* tw = slab[wid];

    for (int s = 0; s < 8; ++s) {
        int rb = blockIdx.x * 128 + s * 16;   // slab's 16 rows

        // A fragments + x2 partials for this slab (all 4 waves load the
        // same 8KB of x -> L1/L2 dedupe).
        bf16x8 a[4];
        float x2p = 0.f;
        #pragma unroll
        for (int ks = 0; ks < 4; ++ks)
            a[ks] = load_frag_x2(
                &x[(size_t)(rb + l16) * INF + ks * 32 + lq * 8], x2p);
        x2p += __shfl_xor(x2p, 16);
        x2p += __shfl_xor(x2p, 32);
        float x2row[4];
        #pragma unroll
        for (int r = 0; r < 4; ++r)
            x2row[r] = __shfl(x2p, lq * 20 + r);

        // GEMM: 16 rows x 256 cols, K=128.
        f32x4 acc[16];
        #pragma unroll
        for (int in = 0; in < 16; ++in)
            acc[in] = f32x4{0.f, 0.f, 0.f, 0.f};
        #pragma unroll
        for (int ks = 0; ks < 4; ++ks) {
            bf16x8 b[16];
            #pragma unroll
            for (int in = 0; in < 16; ++in)
                b[in] = *(const bf16x8*)(
                    wb + (size_t)(c0 + in * 16 + l16) * INF + ks * 32 + lq * 8);
            #pragma unroll
            for (int in = 0; in < 16; ++in)
                acc[in] = __builtin_amdgcn_mfma_f32_16x16x32_bf16(
                    a[ks], b[in], acc[in], 0, 0, 0);
        }

        // Epilogue into wave-private LDS (C/D layout: col=l16, row=lq*4+r).
        // Bank pattern: (16*lq + l16 + const) mod 32 -> 2-way only (free).
        #pragma unroll
        for (int in = 0; in < 16; ++in) {
            #pragma unroll
            for (int r = 0; r < 4; ++r) {
                int row = lq * 4 + r;
                int col = in * 16 + l16;
                float d2 = x2row[r] + sw2[c0 + col] - 2.0f * acc[in][r];
                tw[row * WSTRIDE + col] =
                    -0.5f * __builtin_amdgcn_sqrtf(fmaxf(d2, 0.0f));
            }
        }
        // Intra-wave ds ordering via lgkmcnt; no block barrier.

        // Store: one full 1KB instruction per row (lane-contiguous f32x4);
        // 4 waves complete each 4KB row; 16 rows sweep 64KB sequentially.
        #pragma unroll
        for (int r = 0; r < 16; ++r) {
            f32x4 v = *(const f32x4*)&tw[r * WSTRIDE + lane * 4];
            __builtin_nontemporal_store(
                v, (f32x4*)&out[(size_t)(rb + r) * OUTF + c0 + lane * 4]);
        }
    }
}

extern "C" void kernel_launch(void* const* d_in, const int* in_sizes, int n_in,
                              void* d_out, int out_size, void* d_ws, size_t ws_size,
                              hipStream_t stream) {
    const float* x = (const float*)d_in[0];
    const float* w = (const float*)d_in[1];
    float* out = (float*)d_out;

    // ws layout: w2 [1024 f32] at 0; wb (bf16 W, 256KB) at byte 4096.
    char* ws = (char*)d_ws;
    float* w2 = (float*)ws;
    uint32_t* wb_u32 = (uint32_t*)(ws + 4096);
    const __bf16* wb = (const __bf16*)wb_u32;

    wprep_kernel<<<dim3(OUTF / 4), dim3(256), 0, stream>>>(w, w2, wb_u32);
    fused_kernel<<<dim3(BATCH / 128), dim3(256), 0, stream>>>(x, wb, w2, out);
}

// Round 14
// 80.967 us; speedup vs baseline: 1.9334x; 1.9334x over previous
//
#include <hip/hip_runtime.h>
#include <stdint.h>
#include <stddef.h>

#define BATCH 65536
#define OUTF  1024
#define INF   128

typedef float f32x4 __attribute__((ext_vector_type(4)));
typedef __bf16 bf16x8 __attribute__((ext_vector_type(8)));

// RNE float->bf16, packed pair: lo halfword = a, hi halfword = b
__device__ inline uint32_t pack_bf16_rne(float a, float b) {
    uint32_t ua = __builtin_bit_cast(uint32_t, a);
    uint32_t ub = __builtin_bit_cast(uint32_t, b);
    ua += 0x7fffu + ((ua >> 16) & 1u);
    ub += 0x7fffu + ((ub >> 16) & 1u);
    return (ua >> 16) | (ub & 0xffff0000u);
}

// Prep: one wave per row. Reads fp32 row, writes bf16 row in MFMA FRAGMENT
// ORDER and the row sum-of-squares.
// Swizzled layout (bf16 elems): tile t = row>>4 (16 rows), ks = k>>5,
// frag-lane wl = ((k>>3)&3)*16 + (row&15), elem j = k&7:
//   addr = ((t*4 + ks)*64 + wl)*8 + j
// -> a wave's fragment load in the GEMM is ONE contiguous 1KB instruction.
__global__ __launch_bounds__(256) void prep_kernel(
        const float* __restrict__ x, const float* __restrict__ w,
        float* __restrict__ sumsq, uint32_t* __restrict__ xb,
        uint32_t* __restrict__ wb) {
    int gtid = blockIdx.x * 256 + threadIdx.x;
    int row  = gtid >> 6;
    int lane = threadIdx.x & 63;
    if (row >= BATCH + OUTF) return;
    const float* src;
    uint32_t* dstbase;
    int r;
    if (row < BATCH) {
        src = x + (size_t)row * INF;
        dstbase = xb;
        r = row;
    } else {
        src = w + (size_t)(row - BATCH) * INF;
        dstbase = wb;
        r = row - BATCH;
    }
    float2 v = *(const float2*)(src + lane * 2);   // k = 2*lane, 2*lane+1
    int t    = r >> 4;
    int l16r = r & 15;
    int ks   = lane >> 4;          // (2*lane)>>5
    int lq   = (lane >> 2) & 3;    // ((2*lane)>>3)&3
    int sub  = lane & 3;           // u32 slot within the 8-elem group
    dstbase[(((size_t)t * 4 + ks) * 64 + lq * 16 + l16r) * 4 + sub] =
        pack_bf16_rne(v.x, v.y);
    float s = v.x * v.x + v.y * v.y;
    #pragma unroll
    for (int off = 32; off; off >>= 1) s += __shfl_down(s, off);
    if (lane == 0) sumsq[r + (row < BATCH ? 0 : BATCH)] = s;
}

#define TPAD 132  // LDS row stride (floats)

// 128x128 output tile per block, 4 waves (2x2), mfma 16x16x32 bf16.
// Identical to the 92.7us R4 kernel EXCEPT fragment loads now hit the
// pre-swizzled layout: each A/B fragment = one contiguous 1KB load
// (base + lane*16B) instead of 16 scattered 64B segments at 256B stride.
__global__ __launch_bounds__(256, 2) void gemm_epi_kernel(
        const __bf16* __restrict__ xb, const __bf16* __restrict__ wb,
        const float* __restrict__ x2, const float* __restrict__ w2,
        float* __restrict__ out) {
    // bijective XCD-chunked swizzle: nwg = 4096 (divisible by 8), nt fastest.
    int bid = blockIdx.x;
    int swz = (bid & 7) * (4096 / 8) + (bid >> 3);
    int mt = swz >> 3;          // 512 m-tiles
    int nt = swz & 7;           // 8 n-tiles
    int m0 = mt * 128, n0 = nt * 128;

    int tid  = threadIdx.x;
    int wid  = tid >> 6;
    int lane = tid & 63;
    int wr = wid >> 1, wc = wid & 1;    // 2x2 wave grid, 64x64 per wave
    int ta = (m0 + wr * 64) >> 4;       // A fragment-tile base
    int tb = (n0 + wc * 64) >> 4;       // B fragment-tile base

    __shared__ float sx2[128];
    __shared__ float sw2[128];
    __shared__ float tile[128 * TPAD];
    if (tid < 128) {
        sx2[tid] = x2[m0 + tid];
        sw2[tid] = w2[n0 + tid];
    }
    __syncthreads();

    int l16 = lane & 15;   // fragment row/col (epilogue)
    int lq  = lane >> 4;   // row-quad selector (epilogue)

    f32x4 acc[4][4];
    #pragma unroll
    for (int i = 0; i < 4; ++i)
        #pragma unroll
        for (int j = 0; j < 4; ++j)
            acc[i][j] = f32x4{0.f, 0.f, 0.f, 0.f};

    #pragma unroll
    for (int ks = 0; ks < 4; ++ks) {
        bf16x8 a[4], b[4];
        #pragma unroll
        for (int im = 0; im < 4; ++im)
            a[im] = *(const bf16x8*)(
                xb + (((size_t)(ta + im) * 4 + ks) << 9) + lane * 8);
        #pragma unroll
        for (int in = 0; in < 4; ++in)
            b[in] = *(const bf16x8*)(
                wb + (((size_t)(tb + in) * 4 + ks) << 9) + lane * 8);
        #pragma unroll
        for (int im = 0; im < 4; ++im)
            #pragma unroll
            for (int in = 0; in < 4; ++in)
                acc[im][in] = __builtin_amdgcn_mfma_f32_16x16x32_bf16(
                    a[im], b[in], acc[im][in], 0, 0, 0);
    }

    // Phase 1: fused epilogue math into LDS tile.
    // C/D layout (verified m89/m91): col = lane&15, row = (lane>>4)*4 + reg
    #pragma unroll
    for (int im = 0; im < 4; ++im) {
        #pragma unroll
        for (int in = 0; in < 4; ++in) {
            #pragma unroll
            for (int r = 0; r < 4; ++r) {
                int row = wr * 64 + im * 16 + lq * 4 + r;  // within 128-tile
                int col = wc * 64 + in * 16 + l16;
                float d2 = sx2[row] + sw2[col] - 2.0f * acc[im][in][r];
                tile[row * TPAD + col] = -0.5f * __builtin_amdgcn_sqrtf(fmaxf(d2, 0.0f));
            }
        }
    }
    __syncthreads();

    // Phase 2: coalesced nontemporal float4 stores, 512B contiguous per row.
    int cg = tid & 31;           // col group (16B)
    int r8 = tid >> 5;           // 0..7
    #pragma unroll
    for (int chunk = 0; chunk < 16; ++chunk) {
        int row = chunk * 8 + r8;
        f32x4 v = *(const f32x4*)&tile[row * TPAD + cg * 4];
        __builtin_nontemporal_store(
            v, (f32x4*)&out[(size_t)(m0 + row) * OUTF + n0 + cg * 4]);
    }
}

extern "C" void kernel_launch(void* const* d_in, const int* in_sizes, int n_in,
                              void* d_out, int out_size, void* d_ws, size_t ws_size,
                              hipStream_t stream) {
    const float* x = (const float*)d_in[0];
    const float* w = (const float*)d_in[1];
    float* out = (float*)d_out;

    // ws layout: [0, 66560*4) f32 sumsq (x2 then w2);
    // xb (swizzled bf16 x, 16 MiB) at byte 266240; wb (swizzled) after it.
    char* ws = (char*)d_ws;
    float* sumsq = (float*)ws;
    float* x2 = sumsq;
    float* w2 = sumsq + BATCH;
    uint32_t* xb_u32 = (uint32_t*)(ws + 266240);
    uint32_t* wb_u32 = (uint32_t*)(ws + 266240 + (size_t)BATCH * INF * 2);
    const __bf16* xb = (const __bf16*)xb_u32;
    const __bf16* wb = (const __bf16*)wb_u32;

    prep_kernel<<<dim3((BATCH + OUTF) / 4), dim3(256), 0, stream>>>(
        x, w, sumsq, xb_u32, wb_u32);
    gemm_epi_kernel<<<dim3(4096), dim3(256), 0, stream>>>(xb, wb, x2, w2, out);
}